// Round 29
// baseline (2501.341 us; speedup 1.0000x reference)
//
#include <hip/hip_runtime.h>
#include <hip/hip_bf16.h>
#include <stdint.h>

#define BATCH   256
#define T_STEPS 100
#define IN_DIM  700
#define H_DIM   1024
#define OUT_DIM 20
#define TC      8      // timesteps per chunk
#define NCHUNK  13     // ceil(100/8); chunk 12 covers t=96..99 (+4 guarded)
#define L0_NC   22     // ceil(700/32); joins after c=15 (k=512), c=21 (k=700)
#define L1_NC   32     // 1024/32;      joins after c=15 (k=512), c=31 (k=1024)

// Exactness contract (validated R21-R28): per output element, cur = serial
// ascending fmaf chain in k, straight 512-chunks, one f32 add per chunk join
// (first join exact from 0). LIF: rst=(m>thr)?thr:0; v=0.5f*m+cur; v-=rst;
// spk=(v>thr).  K=700 panels [512,188]; K=1024 panels [512,512].
// Skipping k where bit==0 is exact: fl(x+0)=x, no -0/NaN reachable.
//
// R29 structure: double-buffered LDS (kc=32, [2][64][36], 36.9KB), ONE barrier
// per chunk: write prefetched regs->LDS[cur]; issue next chunk loads (no wait);
// barrier; compute. vmcnt wait lands one full compute phase after issue.
// Safety: buf[c&1] was last READ in compute c-2, finished by all waves before
// they passed barrier c-1 (program order), so writes at iter c race nothing.

// Epilogue for TC=8: tile row r=4ty+i -> b=8by+(ty>>1), ti=(ty&1)*4+i.
// Even ty runs steps 0-3, passes m via shuffle to odd ty (steps 4-7).
__device__ __forceinline__ void lif_epilogue8(
    const float s[4][4], float thr,
    float* __restrict__ mstate, uint16_t* __restrict__ spk_bits,
    int b, int n0, int tbase, int tx, int ty, int ln)
{
    const int half = ty & 1;
    const int g = ty & 3;
    float m[4];
#pragma unroll
    for (int j = 0; j < 4; ++j)
        m[j] = mstate[(size_t)b * H_DIM + n0 + tx + 16 * j];
#pragma unroll
    for (int i = 0; i < 4; ++i) {
#pragma unroll
        for (int j = 0; j < 4; ++j) {
            const float rst = (m[j] > thr) ? thr : 0.f;
            float v = 0.5f * m[j] + s[i][j];
            v = v - rst; m[j] = v;
        }
        const int t = tbase + i;
#pragma unroll
        for (int j = 0; j < 4; ++j) {
            const unsigned long long mask = __ballot(m[j] > thr);
            if (tx == 0 && half == 0 && t < T_STEPS)
                spk_bits[((size_t)t * BATCH + b) * 64 + (n0 >> 4) + j] =
                    (uint16_t)((mask >> (16 * g)) & 0xFFFFull);
        }
    }
#pragma unroll
    for (int j = 0; j < 4; ++j)
        m[j] = __shfl(m[j], half ? (ln - 16) : ln);
#pragma unroll
    for (int i = 0; i < 4; ++i) {
#pragma unroll
        for (int j = 0; j < 4; ++j) {
            const float rst = (m[j] > thr) ? thr : 0.f;
            float v = 0.5f * m[j] + s[i][j];
            v = v - rst; m[j] = v;
        }
        const int t = tbase + 4 + i;
#pragma unroll
        for (int j = 0; j < 4; ++j) {
            const unsigned long long mask = __ballot(m[j] > thr);
            if (tx == 0 && half == 1 && t < T_STEPS)
                spk_bits[((size_t)t * BATCH + b) * 64 + (n0 >> 4) + j] =
                    (uint16_t)((mask >> (16 * g)) & 0xFFFFull);
        }
    }
    if (half == 1) {
#pragma unroll
        for (int j = 0; j < 4; ++j)
            mstate[(size_t)b * H_DIM + n0 + tx + 16 * j] = m[j];
    }
}

// ---- fused: even blockIdx.x -> L0 chunk tc; odd -> L1 chunk tc-1 ----------
// 64x64 tile, 256 thr, 4x4 regs/thread. Grid (32, 32): 2048 rows = 256b x 8t.
__global__ __launch_bounds__(256, 4) void fused_l0_l1(
    const float* __restrict__ x,       // [256][100][700]
    const float* __restrict__ W0,      // [1024][700]
    const float* __restrict__ W1,      // [1024][1024]
    const float* __restrict__ thr0_p,
    const float* __restrict__ thr1_p,
    float* __restrict__ m0state,
    float* __restrict__ m1state,
    uint16_t* __restrict__ spk0_bits,  // [100][256][64]
    uint16_t* __restrict__ spk1_bits,
    int tc)
{
    __shared__ __align__(16) float As[2][64][36];   // stride 144B: reads 2-way tier
    __shared__ __align__(16) float Ws[2][64][36];

    const int tid = threadIdx.x;
    const int tx = tid & 15, ty = tid >> 4, ln = tid & 63;
    const int by = blockIdx.y;
    const bool isL0 = ((blockIdx.x & 1) == 0);      // parity-interleaved layers
    const int n0 = (blockIdx.x >> 1) * 64;
    const int myc = isL0 ? tc : tc - 1;
    if (isL0 && myc >= NCHUNK) return;              // block-uniform exits
    if (!isL0 && myc < 0) return;

    float ps[4][4], s[4][4];
#pragma unroll
    for (int i = 0; i < 4; ++i)
#pragma unroll
        for (int j = 0; j < 4; ++j) { ps[i][j] = 0.f; s[i][j] = 0.f; }

    const int sr = tid >> 2, q4 = tid & 3;          // staging row, quarter
    const int b_s = 8 * by + (sr >> 3);
    int t_s = myc * TC + (sr & 7);
    if (t_s > T_STEPS - 1) t_s = T_STEPS - 1;       // tail clamp (discarded)
    const int b = 8 * by + (ty >> 1);

    if (isL0) {
        const float* xsrc = x + ((size_t)b_s * T_STEPS + t_s) * IN_DIM;
        const float* wsrc = W0 + (size_t)(n0 + sr) * IN_DIM;
        float4 pfa[2], pfw[2];
#pragma unroll
        for (int u = 0; u < 2; ++u) {               // preload chunk 0
            const int k = (q4 * 2 + u) * 4;
            pfa[u] = (k < IN_DIM) ? *(const float4*)(xsrc + k)
                                  : make_float4(0.f, 0.f, 0.f, 0.f);
            pfw[u] = (k < IN_DIM) ? *(const float4*)(wsrc + k)
                                  : make_float4(0.f, 0.f, 0.f, 0.f);
        }
        int cur = 0;
#pragma unroll 1
        for (int c = 0; c < L0_NC; ++c) {
#pragma unroll
            for (int u = 0; u < 2; ++u) {           // commit chunk c
                *(float4*)&As[cur][sr][(q4 * 2 + u) * 4] = pfa[u];
                *(float4*)&Ws[cur][sr][(q4 * 2 + u) * 4] = pfw[u];
            }
            if (c + 1 < L0_NC) {                    // issue chunk c+1 loads
#pragma unroll
                for (int u = 0; u < 2; ++u) {
                    const int k = (c + 1) * 32 + (q4 * 2 + u) * 4;
                    pfa[u] = (k < IN_DIM) ? *(const float4*)(xsrc + k)
                                          : make_float4(0.f, 0.f, 0.f, 0.f);
                    pfw[u] = (k < IN_DIM) ? *(const float4*)(wsrc + k)
                                          : make_float4(0.f, 0.f, 0.f, 0.f);
                }
            }
            __syncthreads();                        // buf[cur] ready
            const int kmax4 = (c == L0_NC - 1) ? 7 : 8;  // tail 28 = 7 f4
            for (int k4 = 0; k4 < kmax4; ++k4) {
                float4 av[4], wv[4];
#pragma unroll
                for (int i = 0; i < 4; ++i)
                    av[i] = *(const float4*)&As[cur][4 * ty + i][k4 * 4];
#pragma unroll
                for (int j = 0; j < 4; ++j)
                    wv[j] = *(const float4*)&Ws[cur][tx + 16 * j][k4 * 4];
#pragma unroll
                for (int i = 0; i < 4; ++i)
#pragma unroll
                    for (int j = 0; j < 4; ++j) {
                        ps[i][j] = __builtin_fmaf(av[i].x, wv[j].x, ps[i][j]);
                        ps[i][j] = __builtin_fmaf(av[i].y, wv[j].y, ps[i][j]);
                        ps[i][j] = __builtin_fmaf(av[i].z, wv[j].z, ps[i][j]);
                        ps[i][j] = __builtin_fmaf(av[i].w, wv[j].w, ps[i][j]);
                    }
            }
            if (c == 15 || c == L0_NC - 1) {        // BLIS joins k=512, 700
#pragma unroll
                for (int i = 0; i < 4; ++i)
#pragma unroll
                    for (int j = 0; j < 4; ++j) { s[i][j] += ps[i][j]; ps[i][j] = 0.f; }
            }
            cur ^= 1;
        }
        lif_epilogue8(s, *thr0_p, m0state, spk0_bits, b, n0, myc * TC, tx, ty, ln);
    } else {
        const uint16_t* bsrc = spk0_bits + ((size_t)t_s * BATCH + b_s) * 64;
        const float* wsrc = W1 + (size_t)(n0 + sr) * H_DIM;
        uint32_t pfb;                               // 8 bits at (q4*8) of pair
        float4 pfw[2];
        pfb = (*(const uint32_t*)(bsrc)) >> (q4 * 8);
#pragma unroll
        for (int u = 0; u < 2; ++u)
            pfw[u] = *(const float4*)(wsrc + (q4 * 2 + u) * 4);
        int cur = 0;
#pragma unroll 1
        for (int c = 0; c < L1_NC; ++c) {
            {                                       // commit chunk c
                const uint32_t w = pfb;
#pragma unroll
                for (int u = 0; u < 2; ++u) {
                    float4 v;
                    v.x = ((w >> (u * 4 + 0)) & 1u) ? 1.0f : 0.0f;
                    v.y = ((w >> (u * 4 + 1)) & 1u) ? 1.0f : 0.0f;
                    v.z = ((w >> (u * 4 + 2)) & 1u) ? 1.0f : 0.0f;
                    v.w = ((w >> (u * 4 + 3)) & 1u) ? 1.0f : 0.0f;
                    *(float4*)&As[cur][sr][(q4 * 2 + u) * 4] = v;
                    *(float4*)&Ws[cur][sr][(q4 * 2 + u) * 4] = pfw[u];
                }
            }
            if (c + 1 < L1_NC) {                    // issue chunk c+1 loads
                pfb = (*(const uint32_t*)(bsrc + (c + 1) * 2)) >> (q4 * 8);
#pragma unroll
                for (int u = 0; u < 2; ++u)
                    pfw[u] = *(const float4*)(wsrc + (c + 1) * 32 + (q4 * 2 + u) * 4);
            }
            __syncthreads();                        // buf[cur] ready
            for (int k4 = 0; k4 < 8; ++k4) {
                float4 av[4], wv[4];
#pragma unroll
                for (int i = 0; i < 4; ++i)
                    av[i] = *(const float4*)&As[cur][4 * ty + i][k4 * 4];
#pragma unroll
                for (int j = 0; j < 4; ++j)
                    wv[j] = *(const float4*)&Ws[cur][tx + 16 * j][k4 * 4];
#pragma unroll
                for (int i = 0; i < 4; ++i)
#pragma unroll
                    for (int j = 0; j < 4; ++j) {
                        ps[i][j] = __builtin_fmaf(av[i].x, wv[j].x, ps[i][j]);
                        ps[i][j] = __builtin_fmaf(av[i].y, wv[j].y, ps[i][j]);
                        ps[i][j] = __builtin_fmaf(av[i].z, wv[j].z, ps[i][j]);
                        ps[i][j] = __builtin_fmaf(av[i].w, wv[j].w, ps[i][j]);
                    }
            }
            if (c == 15 || c == L1_NC - 1) {        // BLIS joins k=512, 1024
#pragma unroll
                for (int i = 0; i < 4; ++i)
#pragma unroll
                    for (int j = 0; j < 4; ++j) { s[i][j] += ps[i][j]; ps[i][j] = 0.f; }
            }
            cur ^= 1;
        }
        lif_epilogue8(s, *thr1_p, m1state, spk1_bits, b, n0, myc * TC, tx, ty, ln);
    }
}

// ---- K2a: output currents; thread = (q, n-quad, half-chain) ---------------
// Exact: half-chains are the BLIS panels; k2b joins them (s = fl(h0+h1)).
__global__ __launch_bounds__(256) void k2a_gemm(
    const uint16_t* __restrict__ spk1_bits,
    const float* __restrict__ W2,     // [20][1024]
    float* __restrict__ cur2h)        // [2][25600][20]
{
    const int gid = blockIdx.x * 256 + threadIdx.x;   // 1000 blocks = 256000
    const int grp = gid / 25600;       // 0..9
    const int q   = gid % 25600;
    const int nq  = grp >> 1;          // n-quad 0..4
    const int h   = grp & 1;           // half-chain

    const uint16_t* bits = spk1_bits + (size_t)q * 64 + h * 32;
    const float* wr0 = W2 + (size_t)(nq * 4 + 0) * H_DIM + h * 512;
    const float* wr1 = W2 + (size_t)(nq * 4 + 1) * H_DIM + h * 512;
    const float* wr2 = W2 + (size_t)(nq * 4 + 2) * H_DIM + h * 512;
    const float* wr3 = W2 + (size_t)(nq * 4 + 3) * H_DIM + h * 512;

    float ps[4] = {0.f, 0.f, 0.f, 0.f};
    for (int wi = 0; wi < 32; ++wi) {
        const uint32_t bw = bits[wi];
        const int kb = wi * 16;
#pragma unroll
        for (int f = 0; f < 4; ++f) {
            const float4 a = *(const float4*)(wr0 + kb + f * 4);
            const float4 bq = *(const float4*)(wr1 + kb + f * 4);
            const float4 cq = *(const float4*)(wr2 + kb + f * 4);
            const float4 dq = *(const float4*)(wr3 + kb + f * 4);
            const int base = f * 4;
            ps[0] += ((bw >> (base + 0)) & 1u) ? a.x : 0.f;
            ps[1] += ((bw >> (base + 0)) & 1u) ? bq.x : 0.f;
            ps[2] += ((bw >> (base + 0)) & 1u) ? cq.x : 0.f;
            ps[3] += ((bw >> (base + 0)) & 1u) ? dq.x : 0.f;
            ps[0] += ((bw >> (base + 1)) & 1u) ? a.y : 0.f;
            ps[1] += ((bw >> (base + 1)) & 1u) ? bq.y : 0.f;
            ps[2] += ((bw >> (base + 1)) & 1u) ? cq.y : 0.f;
            ps[3] += ((bw >> (base + 1)) & 1u) ? dq.y : 0.f;
            ps[0] += ((bw >> (base + 2)) & 1u) ? a.z : 0.f;
            ps[1] += ((bw >> (base + 2)) & 1u) ? bq.z : 0.f;
            ps[2] += ((bw >> (base + 2)) & 1u) ? cq.z : 0.f;
            ps[3] += ((bw >> (base + 2)) & 1u) ? dq.z : 0.f;
            ps[0] += ((bw >> (base + 3)) & 1u) ? a.w : 0.f;
            ps[1] += ((bw >> (base + 3)) & 1u) ? bq.w : 0.f;
            ps[2] += ((bw >> (base + 3)) & 1u) ? cq.w : 0.f;
            ps[3] += ((bw >> (base + 3)) & 1u) ? dq.w : 0.f;
        }
    }
    float* dst = cur2h + ((size_t)h * 25600 + q) * OUT_DIM + nq * 4;
#pragma unroll
    for (int j = 0; j < 4; ++j) dst[j] = ps[j];
}

// ---- K2b: join halves (exact panel join) + LIF recurrence + final writes --
__global__ __launch_bounds__(256) void k2b_lif_out(
    const float* __restrict__ cur2h,   // [2][25600][20]
    const float* __restrict__ thr_p,
    float* __restrict__ out)           // [spk: 100*256*20][mem: 100*256*20]
{
    const int idx = blockIdx.x * 256 + threadIdx.x;
    if (idx >= BATCH * OUT_DIM) return;
    const float thr = *thr_p;
    const size_t stride = (size_t)BATCH * OUT_DIM;
    float m = 0.f;
    for (int t = 0; t < T_STEPS; ++t) {
        const float h0 = cur2h[(size_t)t * stride + idx];
        const float h1 = cur2h[(size_t)25600 * OUT_DIM + (size_t)t * stride + idx];
        const float cur = h0 + h1;             // BLIS join at k=512
        const float rst = (m > thr) ? thr : 0.f;
        float v = 0.5f * m + cur;
        v = v - rst;
        m = v;
        out[(size_t)t * stride + idx] = (v > thr) ? 1.0f : 0.0f;
        out[(size_t)T_STEPS * stride + (size_t)t * stride + idx] = v;
    }
}

extern "C" void kernel_launch(void* const* d_in, const int* in_sizes, int n_in,
                              void* d_out, int out_size, void* d_ws, size_t ws_size,
                              hipStream_t stream)
{
    const float* x    = (const float*)d_in[0];
    const float* W0   = (const float*)d_in[1];
    const float* W1   = (const float*)d_in[2];
    const float* W2   = (const float*)d_in[3];
    const float* thr0 = (const float*)d_in[4];
    const float* thr1 = (const float*)d_in[5];
    const float* thr2 = (const float*)d_in[6];

    // ws (12.75 MB): spk0 3.277 | spk1 3.277 | cur2h 4.096 | m0 1.049 | m1 1.049
    uint16_t* spk0_bits = (uint16_t*)d_ws;
    uint16_t* spk1_bits = spk0_bits + (size_t)T_STEPS * BATCH * 64;
    float*    cur2h     = (float*)(spk1_bits + (size_t)T_STEPS * BATCH * 64);
    float*    m0state   = cur2h + (size_t)2 * 25600 * OUT_DIM;
    float*    m1state   = m0state + (size_t)BATCH * H_DIM;

    hipMemsetAsync(m0state, 0, (size_t)BATCH * H_DIM * 2 * sizeof(float), stream);

    const dim3 grid(32, 32);                     // 1024 blocks: L0|L1 parity mix
    for (int tc = 0; tc <= NCHUNK; ++tc)
        fused_l0_l1<<<grid, 256, 0, stream>>>(
            x, W0, W1, thr0, thr1, m0state, m1state, spk0_bits, spk1_bits, tc);

    k2a_gemm<<<1000, 256, 0, stream>>>(spk1_bits, W2, cur2h);
    k2b_lif_out<<<(BATCH * OUT_DIM + 255) / 256, 256, 0, stream>>>(
        cur2h, thr2, (float*)d_out);
}